// Round 6
// baseline (2058.552 us; speedup 1.0000x reference)
//
#include <hip/hip_runtime.h>
#include <math.h>

#define NPTS 2048
#define NB 8
#define R 4        // rows per thread
#define NW 16      // waves per block = column chunks
#define CCH 128    // columns per chunk (NPTS / NW)
#define MARGIN 30.0f

__device__ __forceinline__ float wexp2(float v) { return __builtin_amdgcn_exp2f(v); }

__device__ __forceinline__ unsigned mort_expand(unsigned v) {
  v &= 1023u;
  v = (v | v << 16) & 0x030000FFu;
  v = (v | v << 8)  & 0x0300F00Fu;
  v = (v | v << 4)  & 0x030C30C3u;
  v = (v | v << 2)  & 0x09249249u;
  return v;
}
__device__ __forceinline__ unsigned mort_q(float v) {
  float t = (v + 6.0f) * (1.0f / 12.0f);
  t = fminf(fmaxf(t, 0.0f), 0.99902344f);
  return (unsigned)(t * 1024.0f);
}

// ---------------------------------------------------------------------------
// Per-cloud Morton sort (bitonic, in LDS) + pack sorted records + zero pot/out.
// Any permutation is semantically valid: softmin runs over all j and the final
// reduction is a mean. Sorting only improves tile-skip locality.
// 16 blocks = {x-batch 0..7, y-batch 0..7}.
// ---------------------------------------------------------------------------
__global__ __launch_bounds__(1024) void emd_sort_init(const float* __restrict__ x,
                                                      const float* __restrict__ y,
                                                      float4* __restrict__ x4,
                                                      float4* __restrict__ y4,
                                                      float* __restrict__ pot0,
                                                      float* __restrict__ out) {
  __shared__ unsigned long long key[NPTS];  // 16 KB
  int c = blockIdx.x;                       // 0..15
  int tid = threadIdx.x;
  const float* src = (c < 8) ? x + c * NPTS * 3 : y + (c - 8) * NPTS * 3;
  float4* dst = (c < 8) ? x4 + c * NPTS : y4 + (c - 8) * NPTS;

  for (int i = tid; i < NPTS; i += 1024) {
    float a0 = src[3 * i], a1 = src[3 * i + 1], a2 = src[3 * i + 2];
    unsigned code = mort_expand(mort_q(a0)) | (mort_expand(mort_q(a1)) << 1) |
                    (mort_expand(mort_q(a2)) << 2);
    key[i] = ((unsigned long long)code << 11) | (unsigned)i;  // idx keeps keys unique
  }
  __syncthreads();
  for (int k = 2; k <= NPTS; k <<= 1) {
    for (int j = k >> 1; j > 0; j >>= 1) {
      int a = ((tid & ~(j - 1)) << 1) | (tid & (j - 1));
      int bb = a | j;
      unsigned long long ka = key[a], kb = key[bb];
      bool up = (a & k) == 0;
      if ((ka > kb) == up) { key[a] = kb; key[bb] = ka; }
      __syncthreads();
    }
  }
  for (int i = tid; i < NPTS; i += 1024) {
    int idx = (int)(key[i] & 2047u);
    float a0 = src[3 * idx], a1 = src[3 * idx + 1], a2 = src[3 * idx + 2];
    dst[i] = make_float4(a0, a1, a2, 0.5f * (a0 * a0 + a1 * a1 + a2 * a2));
  }
#pragma unroll
  for (int i = 0; i < 4; ++i) pot0[c * 4096 + i * 1024 + tid] = 0.0f;
  if (c == 0 && tid == 0) out[0] = 0.0f;
}

// ---------------------------------------------------------------------------
// One Sinkhorn softmin sweep over all 4 matrices (R4 geometry):
// 256 blocks x 1024 threads; block=(mat,b,256-row group); 16 waves = column
// chunks of 128; R=4 rows/thread, broadcast LDS reads (256 pairs per b128).
// SKIP (eps<=0.004): per-16-col bounding-box stats + block row-box; tiles with
// ub < min(running max) - 30 (log2 units) are skipped wave-uniformly.
// Sound: ub >= every s in tile; the tile holding any running max never skips;
// rel. LSE error <= 2048*2^-30.
// ---------------------------------------------------------------------------
template <bool FINAL, bool SKIP>
__global__ __launch_bounds__(1024, 4) void emd_sweep(const float4* __restrict__ x4,
                                                     const float4* __restrict__ y4,
                                                     const float* __restrict__ pot_in,
                                                     float* __restrict__ pot_out,
                                                     float* __restrict__ out,
                                                     float c,            // log2e/eps
                                                     float neg_eps_ln2,  // -eps*ln2
                                                     float eps_logM) {   // eps*log(2048)
  __shared__ union {
    struct {
      float4 colpack[NPTS];        // 32 KB  (y0,y1,y2, (h_j-0.5|y|^2)*c)
      float4 sA[128];              // 2 KB   per-16-col: (cc.xyz, maxw)
      float4 sB[128];              // 2 KB   per-16-col: (ch.xyz, -)
    } mn;
    struct {
      float m[NW][256];            // merge phase (colpack dead)
      float l[NW][256];
    } mg;
  } sh;

  int blk = blockIdx.x;            // 0..255
  int mat = blk >> 6;
  int b = (blk >> 3) & 7;
  int rg = blk & 7;                // 256-row group
  int tid = threadIdx.x;
  int lane = tid & 63;
  int w = tid >> 6;                // 0..15 = column chunk

  const float4* rowp = (mat == 1 || mat == 3) ? y4 : x4;
  const float4* colp = (mat == 0 || mat == 3) ? y4 : x4;
  int hidx = (mat < 2) ? (mat ^ 1) : mat;
  const float* h = pot_in + (hidx * NB + b) * NPTS;
  const float4* colb = colp + b * NPTS;

  // ---- stage columns (+ per-16-col box stats when SKIP) ----
  {
    float4 q = colb[tid];
    float wv = (h[tid] - q.w) * c;
    sh.mn.colpack[tid] = make_float4(q.x, q.y, q.z, wv);
    float4 q2 = colb[tid + 1024];
    float wv2 = (h[tid + 1024] - q2.w) * c;
    sh.mn.colpack[tid + 1024] = make_float4(q2.x, q2.y, q2.z, wv2);
    if (SKIP) {
      float v1[7] = {q.x, q.y, q.z, -q.x, -q.y, -q.z, wv};
      float v2[7] = {q2.x, q2.y, q2.z, -q2.x, -q2.y, -q2.z, wv2};
#pragma unroll
      for (int off = 1; off < 16; off <<= 1) {
#pragma unroll
        for (int u = 0; u < 7; ++u) {
          v1[u] = fmaxf(v1[u], __shfl_xor(v1[u], off));
          v2[u] = fmaxf(v2[u], __shfl_xor(v2[u], off));
        }
      }
      if ((lane & 15) == 0) {
        int t1 = tid >> 4;               // cols [16t,16t+16): hi=v[d], lo=-v[3+d]
        sh.mn.sA[t1] = make_float4(0.5f * (v1[0] - v1[3]), 0.5f * (v1[1] - v1[4]),
                                   0.5f * (v1[2] - v1[5]), v1[6]);
        sh.mn.sB[t1] = make_float4(0.5f * (v1[0] + v1[3]), 0.5f * (v1[1] + v1[4]),
                                   0.5f * (v1[2] + v1[5]), 0.0f);
        int t2 = (tid + 1024) >> 4;
        sh.mn.sA[t2] = make_float4(0.5f * (v2[0] - v2[3]), 0.5f * (v2[1] - v2[4]),
                                   0.5f * (v2[2] - v2[5]), v2[6]);
        sh.mn.sB[t2] = make_float4(0.5f * (v2[0] + v2[3]), 0.5f * (v2[1] + v2[4]),
                                   0.5f * (v2[2] + v2[5]), 0.0f);
      }
    }
  }

  // ---- rows + (SKIP) block row bounding box in scaled coords ----
  int rowbase = rg * 256;
  const float4* rowb = rowp + b * NPTS + rowbase;
  float xs[R][3], m[R], l[R];
#pragma unroll
  for (int r = 0; r < R; ++r) {
    float4 p = rowb[r * 64 + lane];
    xs[r][0] = p.x * c;
    xs[r][1] = p.y * c;
    xs[r][2] = p.z * c;
    l[r] = 0.0f;
  }
  float rc0, rc1, rc2, rca0, rca1, rca2, rha0, rha1, rha2;
  if (SKIP) {
    float lo0 = xs[0][0], lo1 = xs[0][1], lo2 = xs[0][2];
    float hi0 = lo0, hi1 = lo1, hi2 = lo2;
#pragma unroll
    for (int r = 1; r < R; ++r) {
      lo0 = fminf(lo0, xs[r][0]); hi0 = fmaxf(hi0, xs[r][0]);
      lo1 = fminf(lo1, xs[r][1]); hi1 = fmaxf(hi1, xs[r][1]);
      lo2 = fminf(lo2, xs[r][2]); hi2 = fmaxf(hi2, xs[r][2]);
    }
#pragma unroll
    for (int off = 1; off < 64; off <<= 1) {
      lo0 = fminf(lo0, __shfl_xor(lo0, off)); hi0 = fmaxf(hi0, __shfl_xor(hi0, off));
      lo1 = fminf(lo1, __shfl_xor(lo1, off)); hi1 = fmaxf(hi1, __shfl_xor(hi1, off));
      lo2 = fminf(lo2, __shfl_xor(lo2, off)); hi2 = fmaxf(hi2, __shfl_xor(hi2, off));
    }
    rc0 = 0.5f * (lo0 + hi0); rha0 = 0.5f * (hi0 - lo0); rca0 = fabsf(rc0);
    rc1 = 0.5f * (lo1 + hi1); rha1 = 0.5f * (hi1 - lo1); rca1 = fabsf(rc1);
    rc2 = 0.5f * (lo2 + hi2); rha2 = 0.5f * (hi2 - lo2); rca2 = fabsf(rc2);
  }
  __syncthreads();

  // seed running max with true term at col == row index (sorted clouds align)
#pragma unroll
  for (int r = 0; r < R; ++r) {
    float4 d = sh.mn.colpack[rowbase + r * 64 + lane];
    m[r] = fmaf(xs[r][0], d.x, fmaf(xs[r][1], d.y, fmaf(xs[r][2], d.z, d.w)));
  }

  int j0 = w * CCH;
  for (int tt = 0; tt < CCH / 16; ++tt) {   // 8 test-tiles of 16 cols
    if (SKIP) {
      int ti = (j0 >> 4) + tt;
      float4 A = sh.mn.sA[ti];
      float4 Bv = sh.mn.sB[ti];
      // max over row-box x col-box of x.y (exact interval product), + max_w
      float ub = A.w
        + rc0 * A.x + rca0 * Bv.x + rha0 * (fabsf(A.x) + Bv.x)
        + rc1 * A.y + rca1 * Bv.y + rha1 * (fabsf(A.y) + Bv.y)
        + rc2 * A.z + rca2 * Bv.z + rha2 * (fabsf(A.z) + Bv.z);
      float mmin = fminf(fminf(m[0], m[1]), fminf(m[2], m[3]));
      if (__all(ub < mmin - MARGIN)) continue;
    }
#pragma unroll
    for (int half = 0; half < 2; ++half) {
      int jt = j0 + tt * 16 + half * 8;
      float4 q[8];
#pragma unroll
      for (int k = 0; k < 8; ++k) q[k] = sh.mn.colpack[jt + k];
#pragma unroll
      for (int r = 0; r < R; ++r) {
        float s[8];
#pragma unroll
        for (int k = 0; k < 8; ++k)
          s[k] = fmaf(xs[r][0], q[k].x,
                      fmaf(xs[r][1], q[k].y, fmaf(xs[r][2], q[k].z, q[k].w)));
        float t0 = fmaxf(s[0], s[1]), t1 = fmaxf(s[2], s[3]);
        float t2 = fmaxf(s[4], s[5]), t3 = fmaxf(s[6], s[7]);
        float mt = fmaxf(fmaxf(t0, t1), fmaxf(t2, t3));
        float mn = fmaxf(m[r], mt);
        float acc0 = 0.0f, acc1 = 0.0f;
#pragma unroll
        for (int k = 0; k < 8; k += 2) {
          acc0 += wexp2(s[k] - mn);
          acc1 += wexp2(s[k + 1] - mn);
        }
        l[r] = fmaf(l[r], wexp2(m[r] - mn), acc0 + acc1);
        m[r] = mn;
      }
    }
  }

  __syncthreads();  // colpack/stats dead; safe to overwrite (union)
#pragma unroll
  for (int r = 0; r < R; ++r) {
    sh.mg.m[w][r * 64 + lane] = m[r];
    sh.mg.l[w][r * 64 + lane] = l[r];
  }
  __syncthreads();

  if (w < 4) {
    int row = w * 64 + lane;  // 0..255
    float M = sh.mg.m[0][row];
#pragma unroll
    for (int q = 1; q < NW; ++q) M = fmaxf(M, sh.mg.m[q][row]);
    float L = 0.0f;
#pragma unroll
    for (int q = 0; q < NW; ++q)
      L += sh.mg.l[q][row] * wexp2(sh.mg.m[q][row] - M);
    float pwv = rowb[row].w;
    float res = pwv + neg_eps_ln2 * (M + log2f(L)) + eps_logM;
    if (FINAL) {
      float sign = (mat < 2) ? 1.0f : -1.0f;
      float val = sign * res * (1.0f / (float)(NB * NPTS));
#pragma unroll
      for (int off = 32; off; off >>= 1) val += __shfl_xor(val, off);
      if (lane == 0) atomicAdd(out, val);
    } else {
      const float* oldp = pot_in + (mat * NB + b) * NPTS + rowbase;
      float* outp = pot_out + (mat * NB + b) * NPTS + rowbase;
      outp[row] = 0.5f * (oldp[row] + res);
    }
  }
}

// ---------------------------------------------------------------------------
extern "C" void kernel_launch(void* const* d_in, const int* in_sizes, int n_in,
                              void* d_out, int out_size, void* d_ws, size_t ws_size,
                              hipStream_t stream) {
  const float* x = (const float*)d_in[0];
  const float* y = (const float*)d_in[1];
  float* out = (float*)d_out;

  char* ws = (char*)d_ws;
  float4* x4 = (float4*)ws;                        // 256 KB (sorted)
  float4* y4 = (float4*)(ws + 262144);             // 256 KB (sorted)
  float* pot = (float*)(ws + 524288);              // 2 * 65536 floats

  emd_sort_init<<<16, 1024, 0, stream>>>(x, y, x4, y4, pot, out);

  // eps schedule: s=8.0, *=0.9 while s>0.01; eps = f32(s)^2; append 0.01^2
  float eps_arr[80];
  int ne = 0;
  double s = 8.0;
  while (s > 0.01) {
    float sf = (float)s;
    eps_arr[ne++] = sf * sf;
    s *= 0.9;
  }
  {
    float bf = 0.01f;
    eps_arr[ne++] = bf * bf;
  }

  const double LOG2E = 1.4426950408889634;
  const double LN2 = 0.6931471805599453;
  const double LOG2048 = 7.624618986159398;

  int cur = 0;
  for (int k = 0; k < ne; ++k) {
    float eps = eps_arr[k];
    float c = (float)(LOG2E / (double)eps);
    float nel = (float)(-(double)eps * LN2);
    float elM = (float)((double)eps * LOG2048);
    if (eps <= 0.004f)
      emd_sweep<false, true><<<256, 1024, 0, stream>>>(x4, y4, pot + cur * 65536,
                                                       pot + (1 - cur) * 65536, out,
                                                       c, nel, elM);
    else
      emd_sweep<false, false><<<256, 1024, 0, stream>>>(x4, y4, pot + cur * 65536,
                                                        pot + (1 - cur) * 65536, out,
                                                        c, nel, elM);
    cur ^= 1;
  }

  {
    float eps = eps_arr[ne - 1];
    float c = (float)(LOG2E / (double)eps);
    float nel = (float)(-(double)eps * LN2);
    float elM = (float)((double)eps * LOG2048);
    emd_sweep<true, true><<<256, 1024, 0, stream>>>(x4, y4, pot + cur * 65536,
                                                    nullptr, out, c, nel, elM);
  }
}

// Round 7
// 1929.147 us; speedup vs baseline: 1.0671x; 1.0671x over previous
//
#include <hip/hip_runtime.h>
#include <math.h>

#define NPTS 2048
#define NB 8
#define R 4        // rows per thread
#define NW 16      // waves per block = column chunks
#define CCH 128    // columns per chunk (NPTS / NW)

__device__ __forceinline__ float wexp2(float v) { return __builtin_amdgcn_exp2f(v); }

// ---------------------------------------------------------------------------
// init: packed point records (x,y,z, 0.5*|p|^2), zero potentials, zero output.
// ws is re-poisoned before every timed call.
// ---------------------------------------------------------------------------
__global__ __launch_bounds__(256) void emd_init(const float* __restrict__ x,
                                                const float* __restrict__ y,
                                                float4* __restrict__ x4,
                                                float4* __restrict__ y4,
                                                float* __restrict__ pot0,
                                                float* __restrict__ out) {
  int t = blockIdx.x * blockDim.x + threadIdx.x;  // 0..65535
  if (t < NB * NPTS) {
    float a0 = x[3 * t], a1 = x[3 * t + 1], a2 = x[3 * t + 2];
    x4[t] = make_float4(a0, a1, a2, 0.5f * (a0 * a0 + a1 * a1 + a2 * a2));
    float b0 = y[3 * t], b1 = y[3 * t + 1], b2 = y[3 * t + 2];
    y4[t] = make_float4(b0, b1, b2, 0.5f * (b0 * b0 + b1 * b1 + b2 * b2));
  }
  pot0[t] = 0.0f;  // grid exactly covers 4*NB*NPTS
  if (t == 0) out[0] = 0.0f;
}

// ---------------------------------------------------------------------------
// One Sinkhorn softmin sweep over all 4 matrices (R4 geometry, now 2-deep
// software-pipelined):
//   mat 0: rows=x cols=y h=g   -> f_new = 0.5*(f + softmin)
//   mat 1: rows=y cols=x h=f   -> g_new
//   mat 2: rows=x cols=x h=fx  -> fx_new
//   mat 3: rows=y cols=y h=gy  -> gy_new
// 256 blocks x 1024 threads; block=(mat,b,256-row group); 16 waves = 16
// column chunks of 128; R=4 rows/thread; broadcast LDS reads, one b128 feeds
// 256 pairs. Tile t+1's 8x float4 are loaded into a second register buffer
// while tile t computes, so ds_read latency is off the critical path
// (~64 VGPRs of tile state; launch_bounds caps at 128 -> 4 waves/SIMD).
// ---------------------------------------------------------------------------
#define TILE_COMPUTE(Q)                                                        \
  {                                                                            \
    _Pragma("unroll") for (int r = 0; r < R; ++r) {                            \
      float s[8];                                                              \
      _Pragma("unroll") for (int k = 0; k < 8; ++k)                            \
          s[k] = fmaf(xs[r][0], Q[k].x,                                        \
                      fmaf(xs[r][1], Q[k].y, fmaf(xs[r][2], Q[k].z, Q[k].w))); \
      float t0 = fmaxf(s[0], s[1]), t1 = fmaxf(s[2], s[3]);                    \
      float t2 = fmaxf(s[4], s[5]), t3 = fmaxf(s[6], s[7]);                    \
      float mt = fmaxf(fmaxf(t0, t1), fmaxf(t2, t3));                          \
      float mn = fmaxf(m[r], mt);                                              \
      float acc0 = 0.0f, acc1 = 0.0f;                                          \
      _Pragma("unroll") for (int k = 0; k < 8; k += 2) {                       \
        acc0 += wexp2(s[k] - mn);                                              \
        acc1 += wexp2(s[k + 1] - mn);                                          \
      }                                                                        \
      l[r] = fmaf(l[r], wexp2(m[r] - mn), acc0 + acc1);                        \
      m[r] = mn;                                                               \
    }                                                                          \
  }

template <bool FINAL>
__global__ __launch_bounds__(1024, 4) void emd_sweep(const float4* __restrict__ x4,
                                                     const float4* __restrict__ y4,
                                                     const float* __restrict__ pot_in,
                                                     float* __restrict__ pot_out,
                                                     float* __restrict__ out,
                                                     float c,            // log2e/eps
                                                     float neg_eps_ln2,  // -eps*ln2
                                                     float eps_logM) {   // eps*log(2048)
  __shared__ union {
    float4 colpack[NPTS];          // 32 KB (staging + main loop)
    struct {
      float m[NW][256];            // merge phase (colpack dead)
      float l[NW][256];
    } mg;
  } sh;

  int blk = blockIdx.x;            // 0..255
  int mat = blk >> 6;
  int b = (blk >> 3) & 7;
  int rg = blk & 7;                // 256-row group
  int tid = threadIdx.x;
  int lane = tid & 63;
  int w = tid >> 6;                // 0..15 = column chunk

  const float4* rowp = (mat == 1 || mat == 3) ? y4 : x4;
  const float4* colp = (mat == 0 || mat == 3) ? y4 : x4;
  int hidx = (mat < 2) ? (mat ^ 1) : mat;
  const float* h = pot_in + (hidx * NB + b) * NPTS;
  const float4* colb = colp + b * NPTS;

  // stage columns: (y0,y1,y2, (h_j - 0.5|y_j|^2) * c)
  {
    float4 q = colb[tid];
    sh.colpack[tid] = make_float4(q.x, q.y, q.z, (h[tid] - q.w) * c);
    float4 q2 = colb[tid + 1024];
    sh.colpack[tid + 1024] =
        make_float4(q2.x, q2.y, q2.z, (h[tid + 1024] - q2.w) * c);
  }
  __syncthreads();

  int rowbase = rg * 256;
  const float4* rowb = rowp + b * NPTS + rowbase;

  float xs[R][3], m[R], l[R];
#pragma unroll
  for (int r = 0; r < R; ++r) {
    float4 p = rowb[r * 64 + lane];
    xs[r][0] = p.x * c;
    xs[r][1] = p.y * c;
    xs[r][2] = p.z * c;
    m[r] = -INFINITY;
    l[r] = 0.0f;
  }

  int j0 = w * CCH;
  float4 qa[8], qb[8];
#pragma unroll
  for (int k = 0; k < 8; ++k) qa[k] = sh.colpack[j0 + k];  // prologue: tile 0

  // 16 tiles of 8 cols, 2x unrolled ping-pong: load t+1 while computing t.
  // Tile index wraps inside the chunk (&127) so prefetch is always in-bounds;
  // the wrapped tile's compute never happens.
  for (int jt = 0; jt < CCH; jt += 16) {
#pragma unroll
    for (int k = 0; k < 8; ++k) qb[k] = sh.colpack[j0 + ((jt + 8) & 127) + k];
    TILE_COMPUTE(qa);
#pragma unroll
    for (int k = 0; k < 8; ++k) qa[k] = sh.colpack[j0 + ((jt + 16) & 127) + k];
    TILE_COMPUTE(qb);
  }

  __syncthreads();  // colpack dead; safe to overwrite (union)
#pragma unroll
  for (int r = 0; r < R; ++r) {
    sh.mg.m[w][r * 64 + lane] = m[r];
    sh.mg.l[w][r * 64 + lane] = l[r];
  }
  __syncthreads();

  if (w < 4) {
    int row = w * 64 + lane;  // 0..255
    float M = sh.mg.m[0][row];
#pragma unroll
    for (int q = 1; q < NW; ++q) M = fmaxf(M, sh.mg.m[q][row]);
    float L = 0.0f;
#pragma unroll
    for (int q = 0; q < NW; ++q)
      L += sh.mg.l[q][row] * wexp2(sh.mg.m[q][row] - M);
    float pw = rowb[row].w;
    float res = pw + neg_eps_ln2 * (M + log2f(L)) + eps_logM;
    if (FINAL) {
      float sign = (mat < 2) ? 1.0f : -1.0f;
      float val = sign * res * (1.0f / (float)(NB * NPTS));
#pragma unroll
      for (int off = 32; off; off >>= 1) val += __shfl_xor(val, off);
      if (lane == 0) atomicAdd(out, val);
    } else {
      const float* oldp = pot_in + (mat * NB + b) * NPTS + rowbase;
      float* outp = pot_out + (mat * NB + b) * NPTS + rowbase;
      outp[row] = 0.5f * (oldp[row] + res);
    }
  }
}

// ---------------------------------------------------------------------------
extern "C" void kernel_launch(void* const* d_in, const int* in_sizes, int n_in,
                              void* d_out, int out_size, void* d_ws, size_t ws_size,
                              hipStream_t stream) {
  const float* x = (const float*)d_in[0];
  const float* y = (const float*)d_in[1];
  float* out = (float*)d_out;

  char* ws = (char*)d_ws;
  float4* x4 = (float4*)ws;                        // 256 KB
  float4* y4 = (float4*)(ws + 262144);             // 256 KB
  float* pot = (float*)(ws + 524288);              // 2 * 65536 floats

  emd_init<<<256, 256, 0, stream>>>(x, y, x4, y4, pot, out);

  // eps schedule: s=8.0, *=0.9 while s>0.01; eps = f32(s)^2; append 0.01^2
  float eps_arr[80];
  int ne = 0;
  double s = 8.0;
  while (s > 0.01) {
    float sf = (float)s;
    eps_arr[ne++] = sf * sf;
    s *= 0.9;
  }
  {
    float bf = 0.01f;
    eps_arr[ne++] = bf * bf;
  }

  const double LOG2E = 1.4426950408889634;
  const double LN2 = 0.6931471805599453;
  const double LOG2048 = 7.624618986159398;

  int cur = 0;
  for (int k = 0; k < ne; ++k) {
    float eps = eps_arr[k];
    float c = (float)(LOG2E / (double)eps);
    float nel = (float)(-(double)eps * LN2);
    float elM = (float)((double)eps * LOG2048);
    emd_sweep<false><<<256, 1024, 0, stream>>>(x4, y4, pot + cur * 65536,
                                               pot + (1 - cur) * 65536, out,
                                               c, nel, elM);
    cur ^= 1;
  }

  {
    float eps = eps_arr[ne - 1];
    float c = (float)(LOG2E / (double)eps);
    float nel = (float)(-(double)eps * LN2);
    float elM = (float)((double)eps * LOG2048);
    emd_sweep<true><<<256, 1024, 0, stream>>>(x4, y4, pot + cur * 65536,
                                              nullptr, out, c, nel, elM);
  }
}

// Round 8
// 1703.890 us; speedup vs baseline: 1.2081x; 1.1322x over previous
//
#include <hip/hip_runtime.h>
#include <math.h>

#define NPTS 2048
#define NB 8
#define R 4        // rows per thread
#define NW 16      // waves per block = column chunks
#define CCH 128    // columns per chunk (NPTS / NW)

typedef float v2f __attribute__((ext_vector_type(2)));

__device__ __forceinline__ float wexp2(float v) { return __builtin_amdgcn_exp2f(v); }
__device__ __forceinline__ v2f fma2(v2f a, v2f b, v2f c) {
  return __builtin_elementwise_fma(a, b, c);
}
__device__ __forceinline__ v2f max2(v2f a, v2f b) {
  return __builtin_elementwise_max(a, b);
}

// ---------------------------------------------------------------------------
// init: packed point records (x,y,z, 0.5*|p|^2), zero potentials, zero output.
// ---------------------------------------------------------------------------
__global__ __launch_bounds__(256) void emd_init(const float* __restrict__ x,
                                                const float* __restrict__ y,
                                                float4* __restrict__ x4,
                                                float4* __restrict__ y4,
                                                float* __restrict__ pot0,
                                                float* __restrict__ out) {
  int t = blockIdx.x * blockDim.x + threadIdx.x;  // 0..65535
  if (t < NB * NPTS) {
    float a0 = x[3 * t], a1 = x[3 * t + 1], a2 = x[3 * t + 2];
    x4[t] = make_float4(a0, a1, a2, 0.5f * (a0 * a0 + a1 * a1 + a2 * a2));
    float b0 = y[3 * t], b1 = y[3 * t + 1], b2 = y[3 * t + 2];
    y4[t] = make_float4(b0, b1, b2, 0.5f * (b0 * b0 + b1 * b1 + b2 * b2));
  }
  pot0[t] = 0.0f;
  if (t == 0) out[0] = 0.0f;
}

// ---------------------------------------------------------------------------
// One Sinkhorn softmin sweep, packed-fp32 inner loop.
// 256 blocks x 1024 threads; block=(mat,b,256-row group); 16 waves = column
// chunks of 128 cols (64 col-PAIRS); R=4 rows/thread; LDS broadcast reads.
// Column pair p packed as A=(x0,x1,y0,y1), B=(z0,z1,w0,w1) so the dot+bias is
// 3 v_pk_fma_f32 per 2 cols; packed max tree + packed sub + packed acc.
// ---------------------------------------------------------------------------
template <bool FINAL>
__global__ __launch_bounds__(1024, 4) void emd_sweep(const float4* __restrict__ x4,
                                                     const float4* __restrict__ y4,
                                                     const float* __restrict__ pot_in,
                                                     float* __restrict__ pot_out,
                                                     float* __restrict__ out,
                                                     float c,            // log2e/eps
                                                     float neg_eps_ln2,  // -eps*ln2
                                                     float eps_logM) {   // eps*log(2048)
  __shared__ union {
    struct {
      float4 A[NPTS / 2];          // 16 KB  (x0,x1,y0,y1) per col-pair
      float4 B[NPTS / 2];          // 16 KB  (z0,z1,w0,w1), w = (h-0.5|y|^2)*c
    } cp;
    struct {
      float m[NW][256];            // merge phase (colpack dead)
      float l[NW][256];
    } mg;
  } sh;

  int blk = blockIdx.x;            // 0..255
  int mat = blk >> 6;
  int b = (blk >> 3) & 7;
  int rg = blk & 7;                // 256-row group
  int tid = threadIdx.x;
  int lane = tid & 63;
  int w = tid >> 6;                // 0..15 = column chunk

  const float4* rowp = (mat == 1 || mat == 3) ? y4 : x4;
  const float4* colp = (mat == 0 || mat == 3) ? y4 : x4;
  int hidx = (mat < 2) ? (mat ^ 1) : mat;
  const float* h = pot_in + (hidx * NB + b) * NPTS;
  const float4* colb = colp + b * NPTS;

  // stage one column pair per thread
  {
    float4 q0 = colb[2 * tid];
    float4 q1 = colb[2 * tid + 1];
    float2 hv = ((const float2*)h)[tid];
    sh.cp.A[tid] = make_float4(q0.x, q1.x, q0.y, q1.y);
    sh.cp.B[tid] = make_float4(q0.z, q1.z, (hv.x - q0.w) * c, (hv.y - q1.w) * c);
  }
  __syncthreads();

  int rowbase = rg * 256;
  const float4* rowb = rowp + b * NPTS + rowbase;

  v2f xs0[R], xs1[R], xs2[R];
  float m[R], l[R];
#pragma unroll
  for (int r = 0; r < R; ++r) {
    float4 p = rowb[r * 64 + lane];
    float a0 = p.x * c, a1 = p.y * c, a2 = p.z * c;
    xs0[r] = (v2f){a0, a0};
    xs1[r] = (v2f){a1, a1};
    xs2[r] = (v2f){a2, a2};
    m[r] = -INFINITY;
    l[r] = 0.0f;
  }

  int p0 = w * (CCH / 2);          // first col-pair of this chunk
  for (int tp = 0; tp < CCH / 2; tp += 4) {   // tile = 4 pairs = 8 cols
    float4 A[4], B[4];
#pragma unroll
    for (int j = 0; j < 4; ++j) {
      A[j] = sh.cp.A[p0 + tp + j];
      B[j] = sh.cp.B[p0 + tp + j];
    }
#pragma unroll
    for (int r = 0; r < R; ++r) {
      v2f s2[4];
#pragma unroll
      for (int j = 0; j < 4; ++j) {
        v2f qx = {A[j].x, A[j].y};
        v2f qy = {A[j].z, A[j].w};
        v2f qz = {B[j].x, B[j].y};
        v2f qw = {B[j].z, B[j].w};
        s2[j] = fma2(xs0[r], qx, fma2(xs1[r], qy, fma2(xs2[r], qz, qw)));
      }
      v2f t0 = max2(s2[0], s2[1]);
      v2f t1 = max2(s2[2], s2[3]);
      v2f u = max2(t0, t1);
      float mt = fmaxf(u.x, u.y);
      float mn = fmaxf(m[r], mt);
      v2f mn2 = {mn, mn};
      v2f acc = {0.0f, 0.0f};
#pragma unroll
      for (int j = 0; j < 4; ++j) {
        v2f d = s2[j] - mn2;
        v2f e;
        e.x = wexp2(d.x);
        e.y = wexp2(d.y);
        acc += e;
      }
      float er = wexp2(m[r] - mn);
      l[r] = fmaf(l[r], er, acc.x + acc.y);
      m[r] = mn;
    }
  }

  __syncthreads();  // colpack dead; safe to overwrite (union)
#pragma unroll
  for (int r = 0; r < R; ++r) {
    sh.mg.m[w][r * 64 + lane] = m[r];
    sh.mg.l[w][r * 64 + lane] = l[r];
  }
  __syncthreads();

  if (w < 4) {
    int row = w * 64 + lane;  // 0..255
    float M = sh.mg.m[0][row];
#pragma unroll
    for (int q = 1; q < NW; ++q) M = fmaxf(M, sh.mg.m[q][row]);
    float L = 0.0f;
#pragma unroll
    for (int q = 0; q < NW; ++q)
      L += sh.mg.l[q][row] * wexp2(sh.mg.m[q][row] - M);
    float pw = rowb[row].w;
    float res = pw + neg_eps_ln2 * (M + log2f(L)) + eps_logM;
    if (FINAL) {
      float sign = (mat < 2) ? 1.0f : -1.0f;
      float val = sign * res * (1.0f / (float)(NB * NPTS));
#pragma unroll
      for (int off = 32; off; off >>= 1) val += __shfl_xor(val, off);
      if (lane == 0) atomicAdd(out, val);
    } else {
      const float* oldp = pot_in + (mat * NB + b) * NPTS + rowbase;
      float* outp = pot_out + (mat * NB + b) * NPTS + rowbase;
      outp[row] = 0.5f * (oldp[row] + res);
    }
  }
}

// ---------------------------------------------------------------------------
extern "C" void kernel_launch(void* const* d_in, const int* in_sizes, int n_in,
                              void* d_out, int out_size, void* d_ws, size_t ws_size,
                              hipStream_t stream) {
  const float* x = (const float*)d_in[0];
  const float* y = (const float*)d_in[1];
  float* out = (float*)d_out;

  char* ws = (char*)d_ws;
  float4* x4 = (float4*)ws;                        // 256 KB
  float4* y4 = (float4*)(ws + 262144);             // 256 KB
  float* pot = (float*)(ws + 524288);              // 2 * 65536 floats

  emd_init<<<256, 256, 0, stream>>>(x, y, x4, y4, pot, out);

  // eps schedule: s=8.0, *=0.9 while s>0.01; eps = f32(s)^2; append 0.01^2
  float eps_arr[80];
  int ne = 0;
  double s = 8.0;
  while (s > 0.01) {
    float sf = (float)s;
    eps_arr[ne++] = sf * sf;
    s *= 0.9;
  }
  {
    float bf = 0.01f;
    eps_arr[ne++] = bf * bf;
  }

  const double LOG2E = 1.4426950408889634;
  const double LN2 = 0.6931471805599453;
  const double LOG2048 = 7.624618986159398;

  int cur = 0;
  for (int k = 0; k < ne; ++k) {
    float eps = eps_arr[k];
    float c = (float)(LOG2E / (double)eps);
    float nel = (float)(-(double)eps * LN2);
    float elM = (float)((double)eps * LOG2048);
    emd_sweep<false><<<256, 1024, 0, stream>>>(x4, y4, pot + cur * 65536,
                                               pot + (1 - cur) * 65536, out,
                                               c, nel, elM);
    cur ^= 1;
  }

  {
    float eps = eps_arr[ne - 1];
    float c = (float)(LOG2E / (double)eps);
    float nel = (float)(-(double)eps * LN2);
    float elM = (float)((double)eps * LOG2048);
    emd_sweep<true><<<256, 1024, 0, stream>>>(x4, y4, pot + cur * 65536,
                                              nullptr, out, c, nel, elM);
  }
}

// Round 9
// 1438.689 us; speedup vs baseline: 1.4309x; 1.1843x over previous
//
#include <hip/hip_runtime.h>
#include <math.h>

#define NPTS 2048
#define NB 8
#define R 4        // rows per thread
#define NW 16      // waves per block = column chunks
#define CCH 128    // columns per chunk (NPTS / NW)

typedef float v2f __attribute__((ext_vector_type(2)));

__device__ __forceinline__ float wexp2(float v) { return __builtin_amdgcn_exp2f(v); }
__device__ __forceinline__ v2f fma2(v2f a, v2f b, v2f c) {
  return __builtin_elementwise_fma(a, b, c);
}
__device__ __forceinline__ v2f max2(v2f a, v2f b) {
  return __builtin_elementwise_max(a, b);
}

// ---------------------------------------------------------------------------
// init: packed point records (x,y,z, 0.5*|p|^2), zero potentials, zero output.
// ---------------------------------------------------------------------------
__global__ __launch_bounds__(256) void emd_init(const float* __restrict__ x,
                                                const float* __restrict__ y,
                                                float4* __restrict__ x4,
                                                float4* __restrict__ y4,
                                                float* __restrict__ pot0,
                                                float* __restrict__ out) {
  int t = blockIdx.x * blockDim.x + threadIdx.x;  // 0..65535
  if (t < NB * NPTS) {
    float a0 = x[3 * t], a1 = x[3 * t + 1], a2 = x[3 * t + 2];
    x4[t] = make_float4(a0, a1, a2, 0.5f * (a0 * a0 + a1 * a1 + a2 * a2));
    float b0 = y[3 * t], b1 = y[3 * t + 1], b2 = y[3 * t + 2];
    y4[t] = make_float4(b0, b1, b2, 0.5f * (b0 * b0 + b1 * b1 + b2 * b2));
  }
  pot0[t] = 0.0f;
  if (t == 0) out[0] = 0.0f;
}

// ---------------------------------------------------------------------------
// Bootstrap sweep (= proven R8 kernel + per-row amax store). Online softmax,
// exact. Only used for the first eps (no reference max available yet).
// amax_out[row] = (row max of s)/c, unscaled so the next sweep can rescale.
// ---------------------------------------------------------------------------
__global__ __launch_bounds__(1024, 4) void emd_sweep_boot(
    const float4* __restrict__ x4, const float4* __restrict__ y4,
    const float* __restrict__ pot_in, float* __restrict__ pot_out,
    float* __restrict__ amax_out, float c, float neg_eps_ln2, float eps_logM) {
  __shared__ union {
    struct {
      float4 A[NPTS / 2];
      float4 B[NPTS / 2];
    } cp;
    struct {
      float m[NW][256];
      float l[NW][256];
    } mg;
  } sh;

  int blk = blockIdx.x;
  int mat = blk >> 6;
  int b = (blk >> 3) & 7;
  int rg = blk & 7;
  int tid = threadIdx.x;
  int lane = tid & 63;
  int w = tid >> 6;

  const float4* rowp = (mat == 1 || mat == 3) ? y4 : x4;
  const float4* colp = (mat == 0 || mat == 3) ? y4 : x4;
  int hidx = (mat < 2) ? (mat ^ 1) : mat;
  const float* h = pot_in + (hidx * NB + b) * NPTS;
  const float4* colb = colp + b * NPTS;

  {
    float4 q0 = colb[2 * tid];
    float4 q1 = colb[2 * tid + 1];
    float2 hv = ((const float2*)h)[tid];
    sh.cp.A[tid] = make_float4(q0.x, q1.x, q0.y, q1.y);
    sh.cp.B[tid] = make_float4(q0.z, q1.z, (hv.x - q0.w) * c, (hv.y - q1.w) * c);
  }
  __syncthreads();

  int rowbase = rg * 256;
  const float4* rowb = rowp + b * NPTS + rowbase;

  v2f xs0[R], xs1[R], xs2[R];
  float m[R], l[R];
#pragma unroll
  for (int r = 0; r < R; ++r) {
    float4 p = rowb[r * 64 + lane];
    float a0 = p.x * c, a1 = p.y * c, a2 = p.z * c;
    xs0[r] = (v2f){a0, a0};
    xs1[r] = (v2f){a1, a1};
    xs2[r] = (v2f){a2, a2};
    m[r] = -INFINITY;
    l[r] = 0.0f;
  }

  int p0 = w * (CCH / 2);
  for (int tp = 0; tp < CCH / 2; tp += 4) {
    float4 A[4], B[4];
#pragma unroll
    for (int j = 0; j < 4; ++j) {
      A[j] = sh.cp.A[p0 + tp + j];
      B[j] = sh.cp.B[p0 + tp + j];
    }
#pragma unroll
    for (int r = 0; r < R; ++r) {
      v2f s2[4];
#pragma unroll
      for (int j = 0; j < 4; ++j) {
        v2f qx = {A[j].x, A[j].y};
        v2f qy = {A[j].z, A[j].w};
        v2f qz = {B[j].x, B[j].y};
        v2f qw = {B[j].z, B[j].w};
        s2[j] = fma2(xs0[r], qx, fma2(xs1[r], qy, fma2(xs2[r], qz, qw)));
      }
      v2f t0 = max2(s2[0], s2[1]);
      v2f t1 = max2(s2[2], s2[3]);
      v2f u = max2(t0, t1);
      float mt = fmaxf(u.x, u.y);
      float mn = fmaxf(m[r], mt);
      v2f mn2 = {mn, mn};
      v2f acc = {0.0f, 0.0f};
#pragma unroll
      for (int j = 0; j < 4; ++j) {
        v2f d = s2[j] - mn2;
        v2f e;
        e.x = wexp2(d.x);
        e.y = wexp2(d.y);
        acc += e;
      }
      float er = wexp2(m[r] - mn);
      l[r] = fmaf(l[r], er, acc.x + acc.y);
      m[r] = mn;
    }
  }

  __syncthreads();
#pragma unroll
  for (int r = 0; r < R; ++r) {
    sh.mg.m[w][r * 64 + lane] = m[r];
    sh.mg.l[w][r * 64 + lane] = l[r];
  }
  __syncthreads();

  if (w < 4) {
    int row = w * 64 + lane;
    float M = sh.mg.m[0][row];
#pragma unroll
    for (int q = 1; q < NW; ++q) M = fmaxf(M, sh.mg.m[q][row]);
    float L = 0.0f;
#pragma unroll
    for (int q = 0; q < NW; ++q)
      L += sh.mg.l[q][row] * wexp2(sh.mg.m[q][row] - M);
    float pw = rowb[row].w;
    float res = pw + neg_eps_ln2 * (M + log2f(L)) + eps_logM;
    float invc = -neg_eps_ln2;  // = eps*ln2 = 1/c
    amax_out[(mat * NB + b) * NPTS + rowbase + row] = M * invc;
    const float* oldp = pot_in + (mat * NB + b) * NPTS + rowbase;
    float* outp = pot_out + (mat * NB + b) * NPTS + rowbase;
    outp[row] = 0.5f * (oldp[row] + res);
  }
}

// ---------------------------------------------------------------------------
// Fixed-reference sweep: exp2(s - Mref) with Mref = amax_in[row]*c (previous
// sweep's near-max, exact rescaling in c). No online max: no max trees, no
// rescale exps, no max merge. Exact LSE: all terms computed; safe as long as
// |s - Mref| < ~110 log2 units (drift is ~c*dh, orders of magnitude smaller).
// amax_out = (Mref + log2 L)/c  — always in [true max, true max + 11], so the
// reference self-corrects and never accumulates drift.
// ---------------------------------------------------------------------------
template <bool FINAL>
__global__ __launch_bounds__(1024, 4) void emd_sweep_ref(
    const float4* __restrict__ x4, const float4* __restrict__ y4,
    const float* __restrict__ pot_in, float* __restrict__ pot_out,
    const float* __restrict__ amax_in, float* __restrict__ amax_out,
    float* __restrict__ out, float c, float neg_eps_ln2, float eps_logM) {
  __shared__ union {
    struct {
      float4 A[NPTS / 2];          // 16 KB  (x0,x1,y0,y1) per col-pair
      float4 B[NPTS / 2];          // 16 KB  (z0,z1,w0,w1), w=(h-0.5|y|^2)*c
    } cp;
    float lbuf[NW][256];           // merge phase (colpack dead)
  } sh;

  int blk = blockIdx.x;
  int mat = blk >> 6;
  int b = (blk >> 3) & 7;
  int rg = blk & 7;
  int tid = threadIdx.x;
  int lane = tid & 63;
  int w = tid >> 6;

  const float4* rowp = (mat == 1 || mat == 3) ? y4 : x4;
  const float4* colp = (mat == 0 || mat == 3) ? y4 : x4;
  int hidx = (mat < 2) ? (mat ^ 1) : mat;
  const float* h = pot_in + (hidx * NB + b) * NPTS;
  const float4* colb = colp + b * NPTS;

  {
    float4 q0 = colb[2 * tid];
    float4 q1 = colb[2 * tid + 1];
    float2 hv = ((const float2*)h)[tid];
    sh.cp.A[tid] = make_float4(q0.x, q1.x, q0.y, q1.y);
    sh.cp.B[tid] = make_float4(q0.z, q1.z, (hv.x - q0.w) * c, (hv.y - q1.w) * c);
  }

  int rowbase = rg * 256;
  const float4* rowb = rowp + b * NPTS + rowbase;
  const float* amrow = amax_in + (mat * NB + b) * NPTS + rowbase;

  v2f xs0[R], xs1[R], xs2[R], mref2[R], acc[R];
#pragma unroll
  for (int r = 0; r < R; ++r) {
    float4 p = rowb[r * 64 + lane];
    float a0 = p.x * c, a1 = p.y * c, a2 = p.z * c;
    xs0[r] = (v2f){a0, a0};
    xs1[r] = (v2f){a1, a1};
    xs2[r] = (v2f){a2, a2};
    float mr = amrow[r * 64 + lane] * c;  // rescaled reference max
    mref2[r] = (v2f){mr, mr};
    acc[r] = (v2f){0.0f, 0.0f};
  }
  __syncthreads();

  int p0 = w * (CCH / 2);
  for (int tp = 0; tp < CCH / 2; tp += 4) {   // 4 pairs = 8 cols per iter
    float4 A[4], B[4];
#pragma unroll
    for (int j = 0; j < 4; ++j) {
      A[j] = sh.cp.A[p0 + tp + j];
      B[j] = sh.cp.B[p0 + tp + j];
    }
#pragma unroll
    for (int r = 0; r < R; ++r) {
#pragma unroll
      for (int j = 0; j < 4; ++j) {
        v2f qx = {A[j].x, A[j].y};
        v2f qy = {A[j].z, A[j].w};
        v2f qz = {B[j].x, B[j].y};
        v2f qw = {B[j].z, B[j].w};
        v2f s2 = fma2(xs0[r], qx, fma2(xs1[r], qy, fma2(xs2[r], qz, qw)));
        v2f d = s2 - mref2[r];
        v2f e;
        e.x = wexp2(d.x);
        e.y = wexp2(d.y);
        acc[r] += e;
      }
    }
  }

  __syncthreads();  // colpack dead; safe to overwrite (union)
#pragma unroll
  for (int r = 0; r < R; ++r)
    sh.lbuf[w][r * 64 + lane] = acc[r].x + acc[r].y;
  __syncthreads();

  if (w < 4) {
    int row = w * 64 + lane;
    float L = sh.lbuf[0][row];
#pragma unroll
    for (int q = 1; q < NW; ++q) L += sh.lbuf[q][row];
    float mr = amrow[row] * c;
    float lse = mr + log2f(L);          // exact log2-sum-exp of s
    float pw = rowb[row].w;
    float res = pw + neg_eps_ln2 * lse + eps_logM;
    float invc = -neg_eps_ln2;
    if (FINAL) {
      float sign = (mat < 2) ? 1.0f : -1.0f;
      float val = sign * res * (1.0f / (float)(NB * NPTS));
#pragma unroll
      for (int off = 32; off; off >>= 1) val += __shfl_xor(val, off);
      if (lane == 0) atomicAdd(out, val);
    } else {
      amax_out[(mat * NB + b) * NPTS + rowbase + row] = lse * invc;
      const float* oldp = pot_in + (mat * NB + b) * NPTS + rowbase;
      float* outp = pot_out + (mat * NB + b) * NPTS + rowbase;
      outp[row] = 0.5f * (oldp[row] + res);
    }
  }
}

// ---------------------------------------------------------------------------
extern "C" void kernel_launch(void* const* d_in, const int* in_sizes, int n_in,
                              void* d_out, int out_size, void* d_ws, size_t ws_size,
                              hipStream_t stream) {
  const float* x = (const float*)d_in[0];
  const float* y = (const float*)d_in[1];
  float* out = (float*)d_out;

  char* ws = (char*)d_ws;
  float4* x4 = (float4*)ws;                        // 256 KB
  float4* y4 = (float4*)(ws + 262144);             // 256 KB
  float* pot = (float*)(ws + 524288);              // 2 * 65536 floats = 512 KB
  float* amax = (float*)(ws + 1048576);            // 65536 floats = 256 KB

  emd_init<<<256, 256, 0, stream>>>(x, y, x4, y4, pot, out);

  // eps schedule: s=8.0, *=0.9 while s>0.01; eps = f32(s)^2; append 0.01^2
  float eps_arr[80];
  int ne = 0;
  double s = 8.0;
  while (s > 0.01) {
    float sf = (float)s;
    eps_arr[ne++] = sf * sf;
    s *= 0.9;
  }
  {
    float bf = 0.01f;
    eps_arr[ne++] = bf * bf;
  }

  const double LOG2E = 1.4426950408889634;
  const double LN2 = 0.6931471805599453;
  const double LOG2048 = 7.624618986159398;

  int cur = 0;
  for (int k = 0; k < ne; ++k) {
    float eps = eps_arr[k];
    float c = (float)(LOG2E / (double)eps);
    float nel = (float)(-(double)eps * LN2);
    float elM = (float)((double)eps * LOG2048);
    if (k == 0) {
      emd_sweep_boot<<<256, 1024, 0, stream>>>(x4, y4, pot + cur * 65536,
                                               pot + (1 - cur) * 65536, amax,
                                               c, nel, elM);
    } else {
      emd_sweep_ref<false><<<256, 1024, 0, stream>>>(
          x4, y4, pot + cur * 65536, pot + (1 - cur) * 65536, amax, amax, out,
          c, nel, elM);
    }
    cur ^= 1;
  }

  {
    float eps = eps_arr[ne - 1];
    float c = (float)(LOG2E / (double)eps);
    float nel = (float)(-(double)eps * LN2);
    float elM = (float)((double)eps * LOG2048);
    emd_sweep_ref<true><<<256, 1024, 0, stream>>>(
        x4, y4, pot + cur * 65536, nullptr, amax, nullptr, out, c, nel, elM);
  }
}

// Round 10
// 1377.763 us; speedup vs baseline: 1.4941x; 1.0442x over previous
//
#include <hip/hip_runtime.h>
#include <math.h>

#define NPTS 2048
#define NB 8
#define R 2        // rows per thread
#define NW 16      // waves per block = column chunks
#define BROWS 128  // rows per block
#define CPAIR 64   // col-pairs per wave chunk (128 cols)

typedef float v2f __attribute__((ext_vector_type(2)));

__device__ __forceinline__ float wexp2(float v) { return __builtin_amdgcn_exp2f(v); }
__device__ __forceinline__ v2f fma2(v2f a, v2f b, v2f c) {
  return __builtin_elementwise_fma(a, b, c);
}
__device__ __forceinline__ v2f max2(v2f a, v2f b) {
  return __builtin_elementwise_max(a, b);
}

// ---------------------------------------------------------------------------
// init: packed point records (x,y,z, 0.5*|p|^2), zero potentials, zero output.
// ---------------------------------------------------------------------------
__global__ __launch_bounds__(256) void emd_init(const float* __restrict__ x,
                                                const float* __restrict__ y,
                                                float4* __restrict__ x4,
                                                float4* __restrict__ y4,
                                                float* __restrict__ pot0,
                                                float* __restrict__ out) {
  int t = blockIdx.x * blockDim.x + threadIdx.x;  // 0..65535
  if (t < NB * NPTS) {
    float a0 = x[3 * t], a1 = x[3 * t + 1], a2 = x[3 * t + 2];
    x4[t] = make_float4(a0, a1, a2, 0.5f * (a0 * a0 + a1 * a1 + a2 * a2));
    float b0 = y[3 * t], b1 = y[3 * t + 1], b2 = y[3 * t + 2];
    y4[t] = make_float4(b0, b1, b2, 0.5f * (b0 * b0 + b1 * b1 + b2 * b2));
  }
  pot0[t] = 0.0f;
  if (t == 0) out[0] = 0.0f;
}

// ---------------------------------------------------------------------------
// Shared geometry: 512 blocks x 1024 threads; block=(mat,b,128-row group);
// 16 waves = column chunks of 128 cols (64 pairs); R=2 rows/thread.
// 2 blocks/CU co-resident -> 8 waves/SIMD, interleaved barrier domains.
// Column pair packed A=(x0,x1,y0,y1), B=(z0,z1,w0,w1), w=(h-0.5|y|^2)*c.
// ---------------------------------------------------------------------------

// Bootstrap sweep: exact online softmax (first eps only) + amax store.
__global__ __launch_bounds__(1024, 8) void emd_sweep_boot(
    const float4* __restrict__ x4, const float4* __restrict__ y4,
    const float* __restrict__ pot_in, float* __restrict__ pot_out,
    float* __restrict__ amax_out, float c, float neg_eps_ln2, float eps_logM) {
  __shared__ union {
    struct {
      float4 A[NPTS / 2];
      float4 B[NPTS / 2];
    } cp;
    struct {
      float m[NW][BROWS];
      float l[NW][BROWS];
    } mg;
  } sh;

  int blk = blockIdx.x;            // 0..511
  int mat = blk >> 7;
  int b = (blk >> 4) & 7;
  int rg = blk & 15;               // 128-row group
  int tid = threadIdx.x;
  int lane = tid & 63;
  int w = tid >> 6;                // 0..15

  const float4* rowp = (mat == 1 || mat == 3) ? y4 : x4;
  const float4* colp = (mat == 0 || mat == 3) ? y4 : x4;
  int hidx = (mat < 2) ? (mat ^ 1) : mat;
  const float* h = pot_in + (hidx * NB + b) * NPTS;
  const float4* colb = colp + b * NPTS;

  {
    float4 q0 = colb[2 * tid];
    float4 q1 = colb[2 * tid + 1];
    float2 hv = ((const float2*)h)[tid];
    sh.cp.A[tid] = make_float4(q0.x, q1.x, q0.y, q1.y);
    sh.cp.B[tid] = make_float4(q0.z, q1.z, (hv.x - q0.w) * c, (hv.y - q1.w) * c);
  }
  __syncthreads();

  int rowbase = rg * BROWS;
  const float4* rowb = rowp + b * NPTS + rowbase;

  v2f xs0[R], xs1[R], xs2[R];
  float m[R], l[R];
#pragma unroll
  for (int r = 0; r < R; ++r) {
    float4 p = rowb[r * 64 + lane];
    float a0 = p.x * c, a1 = p.y * c, a2 = p.z * c;
    xs0[r] = (v2f){a0, a0};
    xs1[r] = (v2f){a1, a1};
    xs2[r] = (v2f){a2, a2};
    m[r] = -INFINITY;
    l[r] = 0.0f;
  }

  int p0 = w * CPAIR;
  for (int tp = 0; tp < CPAIR; tp += 4) {
    float4 A[4], B[4];
#pragma unroll
    for (int j = 0; j < 4; ++j) {
      A[j] = sh.cp.A[p0 + tp + j];
      B[j] = sh.cp.B[p0 + tp + j];
    }
#pragma unroll
    for (int r = 0; r < R; ++r) {
      v2f s2[4];
#pragma unroll
      for (int j = 0; j < 4; ++j) {
        v2f qx = {A[j].x, A[j].y};
        v2f qy = {A[j].z, A[j].w};
        v2f qz = {B[j].x, B[j].y};
        v2f qw = {B[j].z, B[j].w};
        s2[j] = fma2(xs0[r], qx, fma2(xs1[r], qy, fma2(xs2[r], qz, qw)));
      }
      v2f t0 = max2(s2[0], s2[1]);
      v2f t1 = max2(s2[2], s2[3]);
      v2f u = max2(t0, t1);
      float mt = fmaxf(u.x, u.y);
      float mn = fmaxf(m[r], mt);
      v2f mn2 = {mn, mn};
      v2f acc = {0.0f, 0.0f};
#pragma unroll
      for (int j = 0; j < 4; ++j) {
        v2f d = s2[j] - mn2;
        v2f e;
        e.x = wexp2(d.x);
        e.y = wexp2(d.y);
        acc += e;
      }
      float er = wexp2(m[r] - mn);
      l[r] = fmaf(l[r], er, acc.x + acc.y);
      m[r] = mn;
    }
  }

  __syncthreads();
#pragma unroll
  for (int r = 0; r < R; ++r) {
    sh.mg.m[w][r * 64 + lane] = m[r];
    sh.mg.l[w][r * 64 + lane] = l[r];
  }
  __syncthreads();

  if (w < 2) {
    int row = w * 64 + lane;       // 0..127
    float M = sh.mg.m[0][row];
#pragma unroll
    for (int q = 1; q < NW; ++q) M = fmaxf(M, sh.mg.m[q][row]);
    float L = 0.0f;
#pragma unroll
    for (int q = 0; q < NW; ++q)
      L += sh.mg.l[q][row] * wexp2(sh.mg.m[q][row] - M);
    float pw = rowb[row].w;
    float res = pw + neg_eps_ln2 * (M + log2f(L)) + eps_logM;
    float invc = -neg_eps_ln2;     // = 1/c
    amax_out[(mat * NB + b) * NPTS + rowbase + row] = M * invc;
    const float* oldp = pot_in + (mat * NB + b) * NPTS + rowbase;
    float* outp = pot_out + (mat * NB + b) * NPTS + rowbase;
    outp[row] = 0.5f * (oldp[row] + res);
  }
}

// Fixed-reference sweep: exp2(s - Mref), Mref = amax_in[row]*c. Exact LSE;
// amax_out = (Mref + log2 L)/c self-corrects (always within +11 of true max).
template <bool FINAL>
__global__ __launch_bounds__(1024, 8) void emd_sweep_ref(
    const float4* __restrict__ x4, const float4* __restrict__ y4,
    const float* __restrict__ pot_in, float* __restrict__ pot_out,
    const float* __restrict__ amax_in, float* __restrict__ amax_out,
    float* __restrict__ out, float c, float neg_eps_ln2, float eps_logM) {
  __shared__ union {
    struct {
      float4 A[NPTS / 2];          // 16 KB
      float4 B[NPTS / 2];          // 16 KB
    } cp;
    float lbuf[NW][BROWS];         // merge phase (colpack dead)
  } sh;

  int blk = blockIdx.x;            // 0..511
  int mat = blk >> 7;
  int b = (blk >> 4) & 7;
  int rg = blk & 15;
  int tid = threadIdx.x;
  int lane = tid & 63;
  int w = tid >> 6;

  const float4* rowp = (mat == 1 || mat == 3) ? y4 : x4;
  const float4* colp = (mat == 0 || mat == 3) ? y4 : x4;
  int hidx = (mat < 2) ? (mat ^ 1) : mat;
  const float* h = pot_in + (hidx * NB + b) * NPTS;
  const float4* colb = colp + b * NPTS;

  {
    float4 q0 = colb[2 * tid];
    float4 q1 = colb[2 * tid + 1];
    float2 hv = ((const float2*)h)[tid];
    sh.cp.A[tid] = make_float4(q0.x, q1.x, q0.y, q1.y);
    sh.cp.B[tid] = make_float4(q0.z, q1.z, (hv.x - q0.w) * c, (hv.y - q1.w) * c);
  }

  int rowbase = rg * BROWS;
  const float4* rowb = rowp + b * NPTS + rowbase;
  const float* amrow = amax_in + (mat * NB + b) * NPTS + rowbase;

  v2f xs0[R], xs1[R], xs2[R], mref2[R], acc[R];
#pragma unroll
  for (int r = 0; r < R; ++r) {
    float4 p = rowb[r * 64 + lane];
    float a0 = p.x * c, a1 = p.y * c, a2 = p.z * c;
    xs0[r] = (v2f){a0, a0};
    xs1[r] = (v2f){a1, a1};
    xs2[r] = (v2f){a2, a2};
    float mr = amrow[r * 64 + lane] * c;
    mref2[r] = (v2f){mr, mr};
    acc[r] = (v2f){0.0f, 0.0f};
  }
  __syncthreads();

  int p0 = w * CPAIR;
  for (int tp = 0; tp < CPAIR; tp += 4) {   // 4 pairs = 8 cols per iter
    float4 A[4], B[4];
#pragma unroll
    for (int j = 0; j < 4; ++j) {
      A[j] = sh.cp.A[p0 + tp + j];
      B[j] = sh.cp.B[p0 + tp + j];
    }
#pragma unroll
    for (int r = 0; r < R; ++r) {
#pragma unroll
      for (int j = 0; j < 4; ++j) {
        v2f qx = {A[j].x, A[j].y};
        v2f qy = {A[j].z, A[j].w};
        v2f qz = {B[j].x, B[j].y};
        v2f qw = {B[j].z, B[j].w};
        v2f s2 = fma2(xs0[r], qx, fma2(xs1[r], qy, fma2(xs2[r], qz, qw)));
        v2f d = s2 - mref2[r];
        v2f e;
        e.x = wexp2(d.x);
        e.y = wexp2(d.y);
        acc[r] += e;
      }
    }
  }

  __syncthreads();  // colpack dead; safe to overwrite (union)
#pragma unroll
  for (int r = 0; r < R; ++r)
    sh.lbuf[w][r * 64 + lane] = acc[r].x + acc[r].y;
  __syncthreads();

  if (w < 2) {
    int row = w * 64 + lane;       // 0..127
    float L = sh.lbuf[0][row];
#pragma unroll
    for (int q = 1; q < NW; ++q) L += sh.lbuf[q][row];
    float mr = amrow[row] * c;
    float lse = mr + log2f(L);
    float pw = rowb[row].w;
    float res = pw + neg_eps_ln2 * lse + eps_logM;
    float invc = -neg_eps_ln2;
    if (FINAL) {
      float sign = (mat < 2) ? 1.0f : -1.0f;
      float val = sign * res * (1.0f / (float)(NB * NPTS));
#pragma unroll
      for (int off = 32; off; off >>= 1) val += __shfl_xor(val, off);
      if (lane == 0) atomicAdd(out, val);
    } else {
      amax_out[(mat * NB + b) * NPTS + rowbase + row] = lse * invc;
      const float* oldp = pot_in + (mat * NB + b) * NPTS + rowbase;
      float* outp = pot_out + (mat * NB + b) * NPTS + rowbase;
      outp[row] = 0.5f * (oldp[row] + res);
    }
  }
}

// ---------------------------------------------------------------------------
extern "C" void kernel_launch(void* const* d_in, const int* in_sizes, int n_in,
                              void* d_out, int out_size, void* d_ws, size_t ws_size,
                              hipStream_t stream) {
  const float* x = (const float*)d_in[0];
  const float* y = (const float*)d_in[1];
  float* out = (float*)d_out;

  char* ws = (char*)d_ws;
  float4* x4 = (float4*)ws;                        // 256 KB
  float4* y4 = (float4*)(ws + 262144);             // 256 KB
  float* pot = (float*)(ws + 524288);              // 2 * 65536 floats = 512 KB
  float* amax = (float*)(ws + 1048576);            // 65536 floats = 256 KB

  emd_init<<<256, 256, 0, stream>>>(x, y, x4, y4, pot, out);

  // eps schedule: s=8.0, *=0.9 while s>0.01; eps = f32(s)^2; append 0.01^2
  float eps_arr[80];
  int ne = 0;
  double s = 8.0;
  while (s > 0.01) {
    float sf = (float)s;
    eps_arr[ne++] = sf * sf;
    s *= 0.9;
  }
  {
    float bf = 0.01f;
    eps_arr[ne++] = bf * bf;
  }

  const double LOG2E = 1.4426950408889634;
  const double LN2 = 0.6931471805599453;
  const double LOG2048 = 7.624618986159398;

  int cur = 0;
  for (int k = 0; k < ne; ++k) {
    float eps = eps_arr[k];
    float c = (float)(LOG2E / (double)eps);
    float nel = (float)(-(double)eps * LN2);
    float elM = (float)((double)eps * LOG2048);
    if (k == 0) {
      emd_sweep_boot<<<512, 1024, 0, stream>>>(x4, y4, pot + cur * 65536,
                                               pot + (1 - cur) * 65536, amax,
                                               c, nel, elM);
    } else {
      emd_sweep_ref<false><<<512, 1024, 0, stream>>>(
          x4, y4, pot + cur * 65536, pot + (1 - cur) * 65536, amax, amax, out,
          c, nel, elM);
    }
    cur ^= 1;
  }

  {
    float eps = eps_arr[ne - 1];
    float c = (float)(LOG2E / (double)eps);
    float nel = (float)(-(double)eps * LN2);
    float elM = (float)((double)eps * LOG2048);
    emd_sweep_ref<true><<<512, 1024, 0, stream>>>(
        x4, y4, pot + cur * 65536, nullptr, amax, nullptr, out, c, nel, elM);
  }
}